// Round 1
// baseline (7246.235 us; speedup 1.0000x reference)
//
#include <hip/hip_runtime.h>

typedef __attribute__((ext_vector_type(8))) short short8;
typedef __attribute__((ext_vector_type(4))) float f32x4;
typedef __attribute__((ext_vector_type(4))) float fvec4;
typedef __attribute__((ext_vector_type(4))) unsigned short u16x4;

#define B_ 64
#define T_ 256
#define H_ 512
#define NG 2048   // 4*H
#define BTH (64*256*512)
#define BH (64*512)

__device__ __forceinline__ float bf2f(unsigned short u) {
    return __builtin_bit_cast(float, ((unsigned)u) << 16);
}
__device__ __forceinline__ unsigned short f2bf(float f) {
    unsigned u = __builtin_bit_cast(unsigned, f);
    u += 0x7fffu + ((u >> 16) & 1u);   // RNE
    return (unsigned short)(u >> 16);
}
__device__ __forceinline__ float sigm(float x) { return 1.f / (1.f + __expf(-x)); }
__device__ __forceinline__ float tanh_f(float x) {
    x = fminf(15.f, fmaxf(-15.f, x));
    float e = __expf(-2.f * x);
    return (1.f - e) / (1.f + e);
}

// ---------------- prep: weight transpose f32[K,N] -> bf16[N,K] ----------------
// z: 0=Wi0 1=Wi1 2=Wh0 3=Wh1 ; dst contiguous [z][2048][512]
__global__ void transpose_cvt(const float* __restrict__ Wi, const float* __restrict__ Wh,
                              unsigned short* __restrict__ Wt) {
    __shared__ float tile[64][65];
    int z = blockIdx.z;
    const float* src = (z < 2 ? Wi : Wh) + (size_t)(z & 1) * H_ * NG;
    unsigned short* dst = Wt + (size_t)z * NG * H_;
    int k0 = blockIdx.x * 64, n0 = blockIdx.y * 64;
    int tx = threadIdx.x & 63, ty = threadIdx.x >> 6;
#pragma unroll
    for (int p = 0; p < 16; ++p) {
        int r = (p << 2) + ty;
        tile[r][tx] = src[(size_t)(k0 + r) * NG + n0 + tx];
    }
    __syncthreads();
#pragma unroll
    for (int p = 0; p < 16; ++p) {
        int r = (p << 2) + ty;
        dst[(size_t)(n0 + r) * H_ + k0 + tx] = f2bf(tile[tx][r]);
    }
}

// ---------------- prep: x f32 -> bf16 ----------------
__global__ void cvt_bf16(const float* __restrict__ x, unsigned short* __restrict__ xb) {
    size_t i = ((size_t)blockIdx.x * 256 + threadIdx.x) * 4;
    fvec4 v = *(const fvec4*)&x[i];
    u16x4 o;
    o[0] = f2bf(v[0]); o[1] = f2bf(v[1]); o[2] = f2bf(v[2]); o[3] = f2bf(v[3]);
    *(u16x4*)&xb[i] = o;
}

// ---------------- big GEMM: Gi[t][b][4H] = A @ Wt^T + bias1 + bias2 (bf16 out) ----------
// A: [16384][512] bf16, row = b*256+t.  Bt: [2048][512] bf16.
__global__ __launch_bounds__(256) void gemm_bt(
    const unsigned short* __restrict__ A, const unsigned short* __restrict__ Bt,
    const float* __restrict__ bias1, const float* __restrict__ bias2,
    unsigned short* __restrict__ C) {
    const int tid = threadIdx.x;
    const int wave = tid >> 6, lane = tid & 63;
    const int quad = lane >> 4, l15 = lane & 15;
    const int row0 = blockIdx.x * 64 + wave * 16;
    const int col0 = blockIdx.y * 64;
    f32x4 acc[4] = {};
    const unsigned short* ap = A + (size_t)(row0 + l15) * H_ + (quad << 3);
    const unsigned short* bp = Bt + (size_t)(col0 + l15) * H_ + (quad << 3);
#pragma unroll
    for (int kk = 0; kk < H_; kk += 32) {
        short8 a = *(const short8*)(ap + kk);
#pragma unroll
        for (int c4 = 0; c4 < 4; ++c4) {
            short8 b = *(const short8*)(bp + (size_t)(c4 << 4) * H_ + kk);
            acc[c4] = __builtin_amdgcn_mfma_f32_16x16x32_bf16(a, b, acc[c4], 0, 0, 0);
        }
    }
#pragma unroll
    for (int c4 = 0; c4 < 4; ++c4) {
        int col = col0 + (c4 << 4) + l15;
        float bs = bias1[col] + bias2[col];
#pragma unroll
        for (int r = 0; r < 4; ++r) {
            int row = row0 + (quad << 2) + r;
            int t = row & 255, b = row >> 8;
            C[((size_t)t * B_ + b) * NG + col] = f2bf(acc[c4][r] + bs);
        }
    }
}

// ---------------- grid barrier (monotonic counter, device scope) ----------------
__device__ __forceinline__ void gbar(unsigned* bar, unsigned target) {
    __threadfence();
    __syncthreads();
    if (threadIdx.x == 0) {
        __hip_atomic_fetch_add(bar, 1u, __ATOMIC_ACQ_REL, __HIP_MEMORY_SCOPE_AGENT);
        while (__hip_atomic_load(bar, __ATOMIC_ACQUIRE, __HIP_MEMORY_SCOPE_AGENT) < target)
            __builtin_amdgcn_s_sleep(1);
    }
    __syncthreads();
    __threadfence();
}

// ---------------- persistent recurrent kernel ----------------
// 32 WGs x 256 thr. WG owns gate cols [j0,j0+16) of all 4 gates; Wh slab register-resident.
// Wave handles m-tile of 16 batch rows. One barrier per step.
__global__ __launch_bounds__(256, 1) void lstm_rec(
    const unsigned short* __restrict__ Gi,   // [T][B][2048] bf16 (incl. both biases)
    const unsigned short* __restrict__ Wt,   // Wh^T [2048][512] bf16
    float* __restrict__ c_state,             // [64][512]
    unsigned short* __restrict__ hb0, unsigned short* __restrict__ hb1,
    unsigned short* __restrict__ out_bf,     // layer0: [b*T+t][512] bf16 (or null)
    float* __restrict__ out_f,               // layer1: [B][T][512] f32 (or null)
    float* __restrict__ hT, float* __restrict__ cT,
    unsigned* __restrict__ bar) {
    const int tid = threadIdx.x;
    const int wave = tid >> 6, lane = tid & 63;
    const int quad = lane >> 4, l15 = lane & 15;
    const int j0 = (int)blockIdx.x << 4;
    const int m0 = wave << 4;

    // register-resident weight fragments: bw[kb*4+g]
    short8 bw[64];
#pragma unroll
    for (int kb = 0; kb < 16; ++kb)
#pragma unroll
        for (int g = 0; g < 4; ++g)
            bw[kb * 4 + g] =
                *(const short8*)&Wt[(size_t)((g << 9) + j0 + l15) * H_ + (kb << 5) + (quad << 3)];

    // zero owned slices of c and h(t=0)
    for (int i = tid; i < 64 * 16; i += 256) {
        int b = i >> 4, j = j0 + (i & 15);
        c_state[(b << 9) + j] = 0.f;
        hb0[(b << 9) + j] = 0;
    }
    unsigned phase = 0;
    gbar(bar, 32u * (++phase));

    for (int t = 0; t < T_; ++t) {
        const unsigned short* __restrict__ hp = (t & 1) ? hb1 : hb0;
        unsigned short* __restrict__ hn = (t & 1) ? hb0 : hb1;

        // prefetch Gi and c (overlaps with MFMA loop)
        float gv[4][4], cold[4];
#pragma unroll
        for (int r = 0; r < 4; ++r) {
            int b = m0 + (quad << 2) + r;
            cold[r] = c_state[(b << 9) + j0 + l15];
#pragma unroll
            for (int g = 0; g < 4; ++g)
                gv[g][r] = bf2f(Gi[((size_t)t * B_ + b) * NG + (g << 9) + j0 + l15]);
        }

        f32x4 acc0 = {}, acc1 = {}, acc2 = {}, acc3 = {};
        const unsigned short* ap = hp + ((size_t)(m0 + l15) << 9) + (quad << 3);
#pragma unroll
        for (int kb = 0; kb < 16; ++kb) {
            short8 a = *(const short8*)(ap + (kb << 5));
            acc0 = __builtin_amdgcn_mfma_f32_16x16x32_bf16(a, bw[kb * 4 + 0], acc0, 0, 0, 0);
            acc1 = __builtin_amdgcn_mfma_f32_16x16x32_bf16(a, bw[kb * 4 + 1], acc1, 0, 0, 0);
            acc2 = __builtin_amdgcn_mfma_f32_16x16x32_bf16(a, bw[kb * 4 + 2], acc2, 0, 0, 0);
            acc3 = __builtin_amdgcn_mfma_f32_16x16x32_bf16(a, bw[kb * 4 + 3], acc3, 0, 0, 0);
        }

#pragma unroll
        for (int r = 0; r < 4; ++r) {
            int b = m0 + (quad << 2) + r;
            int jj = j0 + l15;
            float iv = sigm(acc0[r] + gv[0][r]);
            float fv = sigm(acc1[r] + gv[1][r]);
            float gg = tanh_f(acc2[r] + gv[2][r]);
            float ov = sigm(acc3[r] + gv[3][r]);
            float cn = fv * cold[r] + iv * gg;
            float hv = ov * tanh_f(cn);
            c_state[(b << 9) + jj] = cn;
            hn[(b << 9) + jj] = f2bf(hv);
            if (out_bf) out_bf[((size_t)(b << 8) + t) * H_ + jj] = f2bf(hv);
            if (out_f) out_f[((size_t)(b << 8) + t) * H_ + jj] = hv;
            if (t == T_ - 1) {
                hT[(b << 9) + jj] = hv;
                cT[(b << 9) + jj] = cn;
            }
        }
        gbar(bar, 32u * (++phase));
    }
}

extern "C" void kernel_launch(void* const* d_in, const int* in_sizes, int n_in,
                              void* d_out, int out_size, void* d_ws, size_t ws_size,
                              hipStream_t stream) {
    const float* x  = (const float*)d_in[0];
    const float* Wi = (const float*)d_in[1];
    const float* Wh = (const float*)d_in[2];
    const float* bi = (const float*)d_in[3];
    const float* bh = (const float*)d_in[4];
    float* out = (float*)d_out;

    char* w = (char*)d_ws;
    const size_t NK = (size_t)NG * H_;           // 2048*512 elements
    unsigned short* Wt    = (unsigned short*)w;                 // 4 * NK bf16 = 8 MB
    unsigned short* xb    = Wt + 4 * NK;                        // 16384*512 bf16 = 16 MB
    unsigned short* out0b = xb + (size_t)16384 * H_;            // 16 MB
    unsigned short* Gi    = out0b + (size_t)16384 * H_;         // 16384*2048 bf16 = 64 MB
    float* cst            = (float*)(Gi + (size_t)16384 * NG);  // 128 KB
    unsigned short* h0    = (unsigned short*)(cst + BH);        // 64 KB
    unsigned short* h1    = h0 + BH;                            // 64 KB
    unsigned* bar         = (unsigned*)(h1 + BH);               // counters

    hipMemsetAsync(bar, 0, 256, stream);

    transpose_cvt<<<dim3(8, 32, 4), 256, 0, stream>>>(Wi, Wh, Wt);
    cvt_bf16<<<8192, 256, 0, stream>>>(x, xb);

    // ---- layer 0 ----
    gemm_bt<<<dim3(256, 32), 256, 0, stream>>>(xb, Wt + 0 * NK, bi, bh, Gi);
    lstm_rec<<<32, 256, 0, stream>>>(Gi, Wt + 2 * NK, cst, h0, h1,
                                     out0b, nullptr,
                                     out + BTH + 0 * BH, out + BTH + 2 * BH + 0 * BH, bar);
    // ---- layer 1 ----
    gemm_bt<<<dim3(256, 32), 256, 0, stream>>>(out0b, Wt + 1 * NK, bi + NG, bh + NG, Gi);
    lstm_rec<<<32, 256, 0, stream>>>(Gi, Wt + 3 * NK, cst, h0, h1,
                                     nullptr, out,
                                     out + BTH + 1 * BH, out + BTH + 2 * BH + 1 * BH, bar + 32);
}

// Round 3
// 5575.162 us; speedup vs baseline: 1.2997x; 1.2997x over previous
//
#include <hip/hip_runtime.h>

typedef __attribute__((ext_vector_type(8))) short short8;
typedef __attribute__((ext_vector_type(4))) float f32x4;
typedef __attribute__((ext_vector_type(4))) int   i32x4;
typedef __attribute__((ext_vector_type(4))) float fvec4;
typedef __attribute__((ext_vector_type(4))) unsigned short u16x4;

#define B_ 64
#define T_ 256
#define H_ 512
#define NG 2048   // 4*H
#define BTH (64*256*512)
#define BH (64*512)

__device__ __forceinline__ float bf2f(unsigned short u) {
    return __builtin_bit_cast(float, ((unsigned)u) << 16);
}
__device__ __forceinline__ unsigned short f2bf(float f) {
    unsigned u = __builtin_bit_cast(unsigned, f);
    u += 0x7fffu + ((u >> 16) & 1u);   // RNE
    return (unsigned short)(u >> 16);
}
__device__ __forceinline__ float sigm(float x) { return 1.f / (1.f + __expf(-x)); }
__device__ __forceinline__ float tanh_f(float x) {
    x = fminf(15.f, fmaxf(-15.f, x));
    float e = __expf(-2.f * x);
    return (1.f - e) / (1.f + e);
}

// ---- coherent-point (L3) accesses via relaxed agent-scope atomics: lowered to
// ---- global_load/store ... sc1 — NO cache maintenance instructions emitted ----
__device__ __forceinline__ short8 load_frag_coh(const unsigned* p) {
    i32x4 w;
    w[0] = (int)__hip_atomic_load(p + 0, __ATOMIC_RELAXED, __HIP_MEMORY_SCOPE_AGENT);
    w[1] = (int)__hip_atomic_load(p + 1, __ATOMIC_RELAXED, __HIP_MEMORY_SCOPE_AGENT);
    w[2] = (int)__hip_atomic_load(p + 2, __ATOMIC_RELAXED, __HIP_MEMORY_SCOPE_AGENT);
    w[3] = (int)__hip_atomic_load(p + 3, __ATOMIC_RELAXED, __HIP_MEMORY_SCOPE_AGENT);
    return __builtin_bit_cast(short8, w);
}
__device__ __forceinline__ void store_coh(unsigned* p, unsigned v) {
    __hip_atomic_store(p, v, __ATOMIC_RELAXED, __HIP_MEMORY_SCOPE_AGENT);
}

// ---------------- prep: weight transpose f32[K,N] -> bf16[N,K] ----------------
__global__ void transpose_cvt(const float* __restrict__ Wi, const float* __restrict__ Wh,
                              unsigned short* __restrict__ Wt) {
    __shared__ float tile[64][65];
    int z = blockIdx.z;
    const float* src = (z < 2 ? Wi : Wh) + (size_t)(z & 1) * H_ * NG;
    unsigned short* dst = Wt + (size_t)z * NG * H_;
    int k0 = blockIdx.x * 64, n0 = blockIdx.y * 64;
    int tx = threadIdx.x & 63, ty = threadIdx.x >> 6;
#pragma unroll
    for (int p = 0; p < 16; ++p) {
        int r = (p << 2) + ty;
        tile[r][tx] = src[(size_t)(k0 + r) * NG + n0 + tx];
    }
    __syncthreads();
#pragma unroll
    for (int p = 0; p < 16; ++p) {
        int r = (p << 2) + ty;
        dst[(size_t)(n0 + r) * H_ + k0 + tx] = f2bf(tile[tx][r]);
    }
}

__global__ void cvt_bf16(const float* __restrict__ x, unsigned short* __restrict__ xb) {
    size_t i = ((size_t)blockIdx.x * 256 + threadIdx.x) * 4;
    fvec4 v = *(const fvec4*)&x[i];
    u16x4 o;
    o[0] = f2bf(v[0]); o[1] = f2bf(v[1]); o[2] = f2bf(v[2]); o[3] = f2bf(v[3]);
    *(u16x4*)&xb[i] = o;
}

// ---------------- big GEMM: Gi[t][b][4H] = A @ Wt^T + bias1 + bias2 (bf16 out) ----------
__global__ __launch_bounds__(256) void gemm_bt(
    const unsigned short* __restrict__ A, const unsigned short* __restrict__ Bt,
    const float* __restrict__ bias1, const float* __restrict__ bias2,
    unsigned short* __restrict__ C) {
    const int tid = threadIdx.x;
    const int wave = tid >> 6, lane = tid & 63;
    const int quad = lane >> 4, l15 = lane & 15;
    const int row0 = blockIdx.x * 64 + wave * 16;
    const int col0 = blockIdx.y * 64;
    f32x4 acc[4] = {};
    const unsigned short* ap = A + (size_t)(row0 + l15) * H_ + (quad << 3);
    const unsigned short* bp = Bt + (size_t)(col0 + l15) * H_ + (quad << 3);
#pragma unroll
    for (int kk = 0; kk < H_; kk += 32) {
        short8 a = *(const short8*)(ap + kk);
#pragma unroll
        for (int c4 = 0; c4 < 4; ++c4) {
            short8 b = *(const short8*)(bp + (size_t)(c4 << 4) * H_ + kk);
            acc[c4] = __builtin_amdgcn_mfma_f32_16x16x32_bf16(a, b, acc[c4], 0, 0, 0);
        }
    }
#pragma unroll
    for (int c4 = 0; c4 < 4; ++c4) {
        int col = col0 + (c4 << 4) + l15;
        float bs = bias1[col] + bias2[col];
#pragma unroll
        for (int r = 0; r < 4; ++r) {
            int row = row0 + (quad << 2) + r;
            int t = row & 255, b = row >> 8;
            C[((size_t)t * B_ + b) * NG + col] = f2bf(acc[c4][r] + bs);
        }
    }
}

// ---------------- grid barrier: relaxed atomics only, NO cache maintenance ----------
// __syncthreads drains vmcnt(0) (all sc1 h-stores at L3) before thread0's add.
__device__ __forceinline__ void gbar_lite(unsigned* bar, unsigned target) {
    __syncthreads();
    if (threadIdx.x == 0) {
        __hip_atomic_fetch_add(bar, 1u, __ATOMIC_RELAXED, __HIP_MEMORY_SCOPE_AGENT);
        int spins = 0;
        while (__hip_atomic_load(bar, __ATOMIC_RELAXED, __HIP_MEMORY_SCOPE_AGENT) < target) {
            __builtin_amdgcn_s_sleep(1);
            if (++spins > 200000) break;   // failsafe: deadlock -> wrong answer, not hang
        }
    }
    __syncthreads();
}

// ---------------- persistent recurrent kernel ----------------
// 32 WGs x 256 thr. WG owns gate cols [j0,j0+16) of all 4 gates.
// h exchanged via L3 (u32-packed relaxed agent atomics); c in registers;
// Wh slab pinned into VGPRs; one relaxed barrier per step.
__global__ __launch_bounds__(256, 1) void lstm_rec(
    const unsigned short* __restrict__ Gi,   // [T][B][2048] bf16 (incl. both biases)
    const unsigned short* __restrict__ Wt,   // Wh^T [2048][512] bf16
    unsigned* __restrict__ hb0, unsigned* __restrict__ hb1,  // u32-packed [64][256]
    unsigned short* __restrict__ out_bf,     // layer0: [b*T+t][512] bf16 (or null)
    float* __restrict__ out_f,               // layer1: [B][T][512] f32 (or null)
    float* __restrict__ hT, float* __restrict__ cT,
    unsigned* __restrict__ bar) {
    const int tid = threadIdx.x;
    const int wave = tid >> 6, lane = tid & 63;
    const int quad = lane >> 4, l15 = lane & 15;
    const int j0 = (int)blockIdx.x << 4;
    const int m0 = wave << 4;

    // weight fragments; pin into VGPRs (empty asm tie: no instructions, not remat-able)
    short8 bw[64];
#pragma unroll
    for (int kb = 0; kb < 16; ++kb)
#pragma unroll
        for (int g = 0; g < 4; ++g)
            bw[kb * 4 + g] =
                *(const short8*)&Wt[(size_t)((g << 9) + j0 + l15) * H_ + (kb << 5) + (quad << 3)];
#pragma unroll
    for (int i = 0; i < 64; ++i) asm volatile("" : "+v"(bw[i]));

    // init own h(t=-1) slice to zero (u32-packed: even l15 lanes cover col pairs)
    if (!(l15 & 1)) {
#pragma unroll
        for (int r = 0; r < 4; ++r) {
            int b = m0 + (quad << 2) + r;
            store_coh(&hb0[(b << 8) + ((j0 + l15) >> 1)], 0u);
        }
    }
    float cc[4] = {0.f, 0.f, 0.f, 0.f};

    // prefetch Gi[0] (normal cached loads — L2 is never invalidated in this kernel)
    float gv[4][4];
#pragma unroll
    for (int r = 0; r < 4; ++r) {
        int b = m0 + (quad << 2) + r;
#pragma unroll
        for (int g = 0; g < 4; ++g)
            gv[g][r] = bf2f(Gi[(size_t)b * NG + (g << 9) + j0 + l15]);
    }
    gbar_lite(bar, 32u);

    for (int t = 0; t < T_; ++t) {
        const unsigned* hp = (t & 1) ? hb1 : hb0;
        unsigned* hn = (t & 1) ? hb0 : hb1;

        // A-fragments of h(t-1) from coherent point (row m0+l15, u32-packed)
        const unsigned* ap = hp + ((m0 + l15) << 8) + (quad << 2);
        short8 ha[16];
#pragma unroll
        for (int kb = 0; kb < 16; ++kb) ha[kb] = load_frag_coh(ap + (kb << 4));

        f32x4 acc0 = {}, acc1 = {}, acc2 = {}, acc3 = {};
#pragma unroll
        for (int kb = 0; kb < 16; ++kb) {
            acc0 = __builtin_amdgcn_mfma_f32_16x16x32_bf16(ha[kb], bw[kb * 4 + 0], acc0, 0, 0, 0);
            acc1 = __builtin_amdgcn_mfma_f32_16x16x32_bf16(ha[kb], bw[kb * 4 + 1], acc1, 0, 0, 0);
            acc2 = __builtin_amdgcn_mfma_f32_16x16x32_bf16(ha[kb], bw[kb * 4 + 2], acc2, 0, 0, 0);
            acc3 = __builtin_amdgcn_mfma_f32_16x16x32_bf16(ha[kb], bw[kb * 4 + 3], acc3, 0, 0, 0);
        }

#pragma unroll
        for (int r = 0; r < 4; ++r) {
            int b = m0 + (quad << 2) + r;
            int jj = j0 + l15;
            float iv = sigm(acc0[r] + gv[0][r]);
            float fv = sigm(acc1[r] + gv[1][r]);
            float gg = tanh_f(acc2[r] + gv[2][r]);
            float ov = sigm(acc3[r] + gv[3][r]);
            float cn = fv * cc[r] + iv * gg;
            cc[r] = cn;
            float hv = ov * tanh_f(cn);
            unsigned short hb16 = f2bf(hv);
            unsigned packed = (unsigned)hb16 |
                              (((unsigned)(unsigned short)__shfl_xor((int)hb16, 1)) << 16);
            if (!(l15 & 1))
                store_coh(&hn[(b << 8) + (jj >> 1)], packed);
            if (out_bf) out_bf[((size_t)(b << 8) + t) * H_ + jj] = hb16;
            if (out_f) out_f[((size_t)(b << 8) + t) * H_ + jj] = hv;
            if (t == T_ - 1) {
                hT[((size_t)b << 9) + jj] = hv;
                cT[((size_t)b << 9) + jj] = cn;
            }
        }

        // prefetch Gi[t+1] BEFORE the barrier (hides HBM/L2 latency under the wait)
        int tn = (t + 1) & (T_ - 1);
        float gn[4][4];
#pragma unroll
        for (int r = 0; r < 4; ++r) {
            int b = m0 + (quad << 2) + r;
#pragma unroll
            for (int g = 0; g < 4; ++g)
                gn[g][r] = bf2f(Gi[((size_t)tn * B_ + b) * NG + (g << 9) + j0 + l15]);
        }
        gbar_lite(bar, 32u * (t + 2));
#pragma unroll
        for (int r = 0; r < 4; ++r)
#pragma unroll
            for (int g = 0; g < 4; ++g) gv[g][r] = gn[g][r];
    }
}

extern "C" void kernel_launch(void* const* d_in, const int* in_sizes, int n_in,
                              void* d_out, int out_size, void* d_ws, size_t ws_size,
                              hipStream_t stream) {
    const float* x  = (const float*)d_in[0];
    const float* Wi = (const float*)d_in[1];
    const float* Wh = (const float*)d_in[2];
    const float* bi = (const float*)d_in[3];
    const float* bh = (const float*)d_in[4];
    float* out = (float*)d_out;

    char* w = (char*)d_ws;
    const size_t NK = (size_t)NG * H_;
    unsigned short* Wt    = (unsigned short*)w;                 // 8 MB
    unsigned short* xb    = Wt + 4 * NK;                        // 16 MB
    unsigned short* out0b = xb + (size_t)16384 * H_;            // 16 MB
    unsigned short* Gi    = out0b + (size_t)16384 * H_;         // 64 MB
    unsigned* h0          = (unsigned*)(Gi + (size_t)16384 * NG);  // 64 KB (u32-packed)
    unsigned* h1          = h0 + (BH / 2);                      // 64 KB
    unsigned* bar         = h1 + (BH / 2);                      // counters

    hipMemsetAsync(bar, 0, 256, stream);

    transpose_cvt<<<dim3(8, 32, 4), 256, 0, stream>>>(Wi, Wh, Wt);
    cvt_bf16<<<8192, 256, 0, stream>>>(x, xb);

    // ---- layer 0 ----
    gemm_bt<<<dim3(256, 32), 256, 0, stream>>>(xb, Wt + 0 * NK, bi, bh, Gi);
    lstm_rec<<<32, 256, 0, stream>>>(Gi, Wt + 2 * NK, h0, h1,
                                     out0b, nullptr,
                                     out + BTH + 0 * BH, out + BTH + 2 * BH + 0 * BH, bar);
    // ---- layer 1 ----
    gemm_bt<<<dim3(256, 32), 256, 0, stream>>>(out0b, Wt + 1 * NK, bi + NG, bh + NG, Gi);
    lstm_rec<<<32, 256, 0, stream>>>(Gi, Wt + 3 * NK, h0, h1,
                                     nullptr, out,
                                     out + BTH + 1 * BH, out + BTH + 2 * BH + 1 * BH, bar + 32);
}